// Round 2
// baseline (330.173 us; speedup 1.0000x reference)
//
#include <hip/hip_runtime.h>

#define NN 100000
#define NE 1600000
#define DIN 128
#define DOUT 32
#define SB 256                     // scan block size
#define NBLK ((NN + SB - 1) / SB)  // 391

// ===========================================================================
// Common: degree histogram over edge targets
// ===========================================================================
__global__ void deg_count_kernel(const int* __restrict__ col, int* __restrict__ deg) {
    int e = blockIdx.x * blockDim.x + threadIdx.x;
    if (e < NE) atomicAdd(&deg[col[e]], 1);
}

// ===========================================================================
// CSR path
// ===========================================================================
// per-block sums of deg
__global__ void bsum_kernel(const int* __restrict__ deg, int* __restrict__ bsum) {
    __shared__ int s[SB];
    int i = blockIdx.x * SB + threadIdx.x;
    s[threadIdx.x] = (i < NN) ? deg[i] : 0;
    __syncthreads();
    for (int off = SB >> 1; off > 0; off >>= 1) {
        if (threadIdx.x < off) s[threadIdx.x] += s[threadIdx.x + off];
        __syncthreads();
    }
    if (threadIdx.x == 0) bsum[blockIdx.x] = s[0];
}

// exclusive scan of the NBLK block sums (single block of 512)
__global__ void bscan_kernel(const int* __restrict__ bsum, int* __restrict__ bexc) {
    __shared__ int s[512];
    int t = threadIdx.x;
    int own = (t < NBLK) ? bsum[t] : 0;
    s[t] = own;
    __syncthreads();
    for (int off = 1; off < 512; off <<= 1) {
        int v = (t >= off) ? s[t - off] : 0;
        __syncthreads();
        s[t] += v;
        __syncthreads();
    }
    if (t < NBLK) bexc[t] = s[t] - own;
}

// per-element exclusive offsets + dis = rsqrt(deg+1); cursor aliases deg
// (each element is read exactly once by its own thread before being written)
__global__ void offs_kernel(int* __restrict__ deg_cursor,
                            const int* __restrict__ bexc,
                            int* __restrict__ offs,
                            float* __restrict__ dis) {
    __shared__ int s[SB];
    int t = threadIdx.x;
    int i = blockIdx.x * SB + t;
    int d = (i < NN) ? deg_cursor[i] : 0;
    s[t] = d;
    __syncthreads();
    for (int off = 1; off < SB; off <<= 1) {
        int v = (t >= off) ? s[t - off] : 0;
        __syncthreads();
        s[t] += v;
        __syncthreads();
    }
    if (i < NN) {
        int o = bexc[blockIdx.x] + s[t] - d;  // exclusive prefix
        offs[i] = o;
        deg_cursor[i] = o;                    // becomes the fill cursor
        dis[i] = rsqrtf((float)(d + 1));
        if (i == NN - 1) offs[NN] = o + d;
    }
}

// counting-sort fill: srcs grouped by target node
__global__ void fill_kernel(const int* __restrict__ row, const int* __restrict__ col,
                            int* __restrict__ cursor, int* __restrict__ srcs) {
    int e = blockIdx.x * blockDim.x + threadIdx.x;
    if (e < NE) {
        int c = col[e];
        int p = atomicAdd(&cursor[c], 1);
        srcs[p] = row[e];
    }
}

// ===========================================================================
// xw = x @ W  — LDS-tiled tall-skinny GEMM. 64 rows/block, 256 threads,
// 8 outputs/thread, float4 LDS reads.
// ===========================================================================
#define BM 64
__global__ __launch_bounds__(256)
void xw_kernel(const float* __restrict__ x, const float* __restrict__ W,
               float* __restrict__ xw) {
    __shared__ float Xs[BM * DIN];    // 32 KB
    __shared__ float Ws[DIN * DOUT];  // 16 KB
    int t = threadIdx.x;
    int r0 = blockIdx.x * BM;
    for (int i = t; i < (DIN * DOUT) / 4; i += 256)
        ((float4*)Ws)[i] = ((const float4*)W)[i];
    for (int i = t; i < (BM * DIN) / 4; i += 256) {
        int rr = i >> 5;   // 32 float4 per row
        int cc = i & 31;
        float4 v = make_float4(0.f, 0.f, 0.f, 0.f);
        if (r0 + rr < NN) v = ((const float4*)(x + (size_t)(r0 + rr) * DIN))[cc];
        ((float4*)Xs)[i] = v;
    }
    __syncthreads();
    int d = t & 31, g = t >> 5;
    float acc[8] = {0.f, 0.f, 0.f, 0.f, 0.f, 0.f, 0.f, 0.f};
#pragma unroll 4
    for (int k0 = 0; k0 < DIN; k0 += 4) {
        float w0 = Ws[(k0 + 0) * DOUT + d];
        float w1 = Ws[(k0 + 1) * DOUT + d];
        float w2 = Ws[(k0 + 2) * DOUT + d];
        float w3 = Ws[(k0 + 3) * DOUT + d];
#pragma unroll
        for (int j = 0; j < 8; ++j) {
            float4 xv = *(const float4*)&Xs[(g * 8 + j) * DIN + k0];
            acc[j] += xv.x * w0 + xv.y * w1 + xv.z * w2 + xv.w * w3;
        }
    }
#pragma unroll
    for (int j = 0; j < 8; ++j) {
        int r = r0 + g * 8 + j;
        if (r < NN) xw[(size_t)r * DOUT + d] = acc[j];
    }
}

// ===========================================================================
// Gather-aggregate: one wave per node. lanes = (sub-edge h, dim d).
// out[n] = dc^2*xw[n] + sum_in( dis[r]*dc*xw[r] ) + b
// ===========================================================================
__global__ __launch_bounds__(256)
void aggregate_kernel(const int* __restrict__ offs, const int* __restrict__ srcs,
                      const float* __restrict__ dis, const float* __restrict__ xw,
                      const float* __restrict__ b, float* __restrict__ out) {
    int wid = (int)((blockIdx.x * blockDim.x + threadIdx.x) >> 6);
    if (wid >= NN) return;
    int lane = threadIdx.x & 63;
    int d = lane & 31, h = lane >> 5;
    int s = offs[wid], e = offs[wid + 1];
    float dc = dis[wid];
    float acc = (h == 0) ? dc * xw[(size_t)wid * DOUT + d] : 0.f;  // self-loop
    for (int i = s + h; i < e; i += 2) {
        int r = srcs[i];
        acc += dis[r] * xw[(size_t)r * DOUT + d];
    }
    acc += __shfl_down(acc, 32, 64);
    if (h == 0) out[(size_t)wid * DOUT + d] = acc * dc + b[d];
}

// ===========================================================================
// Fallback path (R1 kernels) if workspace is too small for CSR
// ===========================================================================
__global__ void dis_kernel(const int* __restrict__ deg, float* __restrict__ dis) {
    int i = blockIdx.x * blockDim.x + threadIdx.x;
    if (i < NN) dis[i] = rsqrtf((float)(deg[i] + 1));
}

__global__ void xw_init_kernel(const float* __restrict__ x, const float* __restrict__ W,
                               const float* __restrict__ b, const float* __restrict__ dis,
                               float* __restrict__ xw, float* __restrict__ out) {
    __shared__ float Ws[DIN * DOUT];
    for (int i = threadIdx.x; i < DIN * DOUT; i += blockDim.x) Ws[i] = W[i];
    __syncthreads();
    int idx = blockIdx.x * blockDim.x + threadIdx.x;
    if (idx >= NN * DOUT) return;
    int n = idx >> 5;
    int d = idx & (DOUT - 1);
    const float* xr = x + (long long)n * DIN;
    float acc = 0.f;
#pragma unroll
    for (int k = 0; k < DIN; ++k) acc += xr[k] * Ws[k * DOUT + d];
    xw[idx] = acc;
    float di = dis[n];
    out[idx] = di * di * acc + b[d];
}

__global__ void scatter_kernel(const int* __restrict__ row, const int* __restrict__ col,
                               const float* __restrict__ dis, const float* __restrict__ xw,
                               float* __restrict__ out) {
    long long idx = (long long)blockIdx.x * blockDim.x + threadIdx.x;
    if (idx >= (long long)NE * DOUT) return;
    int e = (int)(idx >> 5);
    int d = (int)(idx & (DOUT - 1));
    int r = row[e];
    int c = col[e];
    float nrm = dis[r] * dis[c];
    atomicAdd(&out[c * DOUT + d], nrm * xw[r * DOUT + d]);
}

// ===========================================================================
extern "C" void kernel_launch(void* const* d_in, const int* in_sizes, int n_in,
                              void* d_out, int out_size, void* d_ws, size_t ws_size,
                              hipStream_t stream) {
    const float* x  = (const float*)d_in[0];
    const int*   ei = (const int*)d_in[1];
    const float* W  = (const float*)d_in[2];
    const float* b  = (const float*)d_in[3];
    float* out = (float*)d_out;

    const int* row = ei;       // edge_index[0] = source
    const int* col = ei + NE;  // edge_index[1] = target

    char* ws = (char*)d_ws;
    // layout (128B-aligned offsets)
    int*   deg  = (int*)(ws + 0);         // 400,000 B (becomes cursor)
    float* dis  = (float*)(ws + 401408);  // 400,000 B
    int*   offs = (int*)(ws + 802816);    // 400,004 B
    int*   bsum = (int*)(ws + 1204224);   //   1,564 B
    int*   bexc = (int*)(ws + 1208320);   //   1,564 B
    int*   srcs = (int*)(ws + 1212416);   // 6,400,000 B
    float* xw   = (float*)(ws + 7612416); // 12,800,000 B
    const size_t WS_NEEDED = 20412416ull;

    hipMemsetAsync(deg, 0, NN * sizeof(int), stream);
    {
        int th = 256, bl = (NE + th - 1) / th;
        deg_count_kernel<<<bl, th, 0, stream>>>(col, deg);
    }

    if (ws_size >= WS_NEEDED) {
        // ---- CSR gather path ----
        bsum_kernel<<<NBLK, SB, 0, stream>>>(deg, bsum);
        bscan_kernel<<<1, 512, 0, stream>>>(bsum, bexc);
        offs_kernel<<<NBLK, SB, 0, stream>>>(deg, bexc, offs, dis);
        {
            int th = 256, bl = (NE + th - 1) / th;
            fill_kernel<<<bl, th, 0, stream>>>(row, col, deg /*cursor*/, srcs);
        }
        {
            int bl = (NN + BM - 1) / BM;
            xw_kernel<<<bl, 256, 0, stream>>>(x, W, xw);
        }
        {
            long long waves = NN;
            int th = 256;
            int bl = (int)((waves * 64 + th - 1) / th);
            aggregate_kernel<<<bl, th, 0, stream>>>(offs, srcs, dis, xw, b, out);
        }
    } else {
        // ---- fallback: atomic scatter path (R1) ----
        {
            int th = 256, bl = (NN + th - 1) / th;
            dis_kernel<<<bl, th, 0, stream>>>(deg, dis);
        }
        {
            int th = 256;
            long long total = (long long)NN * DOUT;
            int bl = (int)((total + th - 1) / th);
            xw_init_kernel<<<bl, th, 0, stream>>>(x, W, b, dis, xw, out);
        }
        {
            int th = 256;
            long long total = (long long)NE * DOUT;
            int bl = (int)((total + th - 1) / th);
            scatter_kernel<<<bl, th, 0, stream>>>(row, col, dis, xw, out);
        }
    }
}